// Round 2
// baseline (97.554 us; speedup 1.0000x reference)
//
#include <hip/hip_runtime.h>
#include <cstdint>

// Problem constants: view1 (B=8, C=4, H=256, W=256) fp32, F 3x3 fp32.
constexpr int Hh = 256, Ww = 256, BCc = 32;
// T4[u(264)][rblk(35)][ch(32)][rw(8)] fp16. ridx = r+8: blk0 = rows -8..-1
// (zero), blk1..32 = rows 0..255, blk33/34 = rows 256..271 (zero). Planes
// u=256..263 fully zero. Strides (bytes): u: 17920, rblk: 512, ch: 16.
constexpr int RBLK = 35;
constexpr int USTRIDE = RBLK * BCc * 8 * 2;    // 17920 B
constexpr int UPLANES = 264;

typedef _Float16 half2v   __attribute__((ext_vector_type(2)));
typedef _Float16 half8v   __attribute__((ext_vector_type(8)));
typedef __fp16   fp16x2   __attribute__((ext_vector_type(2)));
typedef float    float16v __attribute__((ext_vector_type(16)));
typedef uint32_t uint4v   __attribute__((ext_vector_type(4)));

static __device__ inline half2v pack2(float a, float b) {
    fp16x2 r = __builtin_amdgcn_cvt_pkrtz(a, b);
    return __builtin_bit_cast(half2v, r);
}

// ---------------------------------------------------------------------------
// Pack view1 (ch,H,W) f32 -> T4 fp16. Blocks 0..511: (chg 4) x (rblk 32) x
// (utile 4, 64 u): 8ch x 8r x 64u each, single pass; write side is 128B-
// contiguous (8 ch x 16 B). Blocks 512..519: grid-stride zero of pads.
// ---------------------------------------------------------------------------
__global__ __launch_bounds__(256) void fume_pack(const float* __restrict__ in,
                                                 char* __restrict__ T4) {
    const int t   = threadIdx.x;
    const int bid = blockIdx.x;
    if (bid >= 512) {                           // zero pads
        constexpr int NA = UPLANES * 3 * 32;    // blk{0,33,34} x u x ch
        constexpr int NB = 8 * 32 * 32;         // u 256..263 x blk1..32 x ch
        for (int id = (bid - 512) * 256 + t; id < NA + NB; id += 8 * 256) {
            int u, blk, ch;
            if (id < NA) {
                u = id / 96;
                int rem = id - u * 96;
                int bsel = rem >> 5;
                blk = (bsel == 0) ? 0 : (bsel == 1 ? 33 : 34);
                ch = rem & 31;
            } else {
                int id2 = id - NA;
                u = 256 + (id2 >> 10);
                int rem = id2 & 1023;
                blk = 1 + (rem >> 5);
                ch = rem & 31;
            }
            uint4v z = {0, 0, 0, 0};
            *(uint4v*)(T4 + (size_t)u * USTRIDE + blk * 512 + ch * 16) = z;
        }
        return;
    }
    __shared__ float lds[8][8][65];             // [ch][r][u(+pad)]
    const int chg = bid & 3;
    const int r0  = ((bid >> 2) & 31) * 8;      // one rblk
    const int u0  = (bid >> 7) * 64;
    const int blk = (r0 >> 3) + 1;              // ridx = r+8

#pragma unroll
    for (int it = 0; it < 16; ++it) {           // 8ch x 8r x 64u coalesced
        int idx = it * 256 + t;
        int ch = idx >> 9, rr = (idx >> 6) & 7, uu = idx & 63;
        lds[ch][rr][uu] =
            in[(chg * 8 + ch) * (Hh * Ww) + (r0 + rr) * Ww + u0 + uu];
    }
    __syncthreads();
    const int chl = t & 7;
#pragma unroll
    for (int p = 0; p < 2; ++p) {
        int u_l = (t >> 3) + p * 32;            // 0..63
        uint32_t w[4];
#pragma unroll
        for (int j = 0; j < 4; ++j) {
            half2v pr = pack2(lds[chl][2 * j][u_l], lds[chl][2 * j + 1][u_l]);
            __builtin_memcpy(&w[j], &pr, 4);
        }
        uint4v val = {w[0], w[1], w[2], w[3]};
        *(uint4v*)(T4 + (size_t)(u0 + u_l) * USTRIDE + blk * 512
                   + (chg * 8 + chl) * 16) = val;
    }
}

// ---------------------------------------------------------------------------
// MFMA main (R16 = R15 + depth-3 software-pipelined B prefetch).
// Strip = 32 px at row y; one 32x32x16 MFMA per u:
//   A[m=px][k] = tent(vidx_px(u) - (8*(M_u+h) + j)),  k = h*8+j, h=lane>>5
//   B[k][ch=n] = T4[u][M_u+h][ch][j] -> one dwordx4/lane; the wave's 64
//                loads are 1 KB CONTIGUOUS (2 rblks x 32ch x 16B)
//   D[m][n]: col=lane&31(=ch), row=(reg&3)+8*(reg>>2)+4*h (guide-verified)
// M_u per u (coverage needs strip-spread < 6; 32-px span <= 5.69, margin
// 0.31). Chunk split (R14): u-quarters are whole 4-u chunks, interior
// quarters disjoint; final chunk overruns <= hi+3 <= 258 < 264 into zeroed
// u-planes, masked by tents.
// R15: lane l precomputes the per-u window (Mo byte offset, 8*Mf float) for
// u = us+l in ONE vector pass; inner loop fetches via v_readlane (uniform
// idx); B-address is scalar-base + constant-voffset.
// R16: T4 (4.7 MB) > one XCD L2 (4 MB) -> many B loads are ~600-cycle L3
// hits; R15 issued each chunk's loads right before use (vmcnt drain on the
// critical path). Now a 3-buffer ring over 4-u chunks issues chunk c+2's
// loads before computing chunk c: ~8 loads in flight, ~2 compute-spans
// (~400 cyc) of cover per buffer. Addresses, v-recurrence, tent math and
// MFMA order are UNCHANGED -> bit-identical output to R15.
// ---------------------------------------------------------------------------
__global__ __launch_bounds__(256, 4) void fume_mfma(const char* __restrict__ T4,
                                                    const float* __restrict__ Fm,
                                                    float* __restrict__ out) {
    __shared__ float red[4][32][33];
    const int t    = threadIdx.x;
    const int lane = t & 63;
    const int wq   = t >> 6;                    // u-quarter 0..3
    const int px   = lane & 31;                 // pixel (A.m) and channel (B.n)
    const int h    = lane >> 5;                 // k-half: window rows 8h..8h+7
    const int x0   = ((int)blockIdx.x & 7) * 32;
    const int y    = (int)blockIdx.x >> 3;
    const int x    = x0 + px;

    // Own-pixel epipolar line (reference op order).
    float xf = (float)x, yf = (float)y;
    float a = Fm[0] * xf + Fm[3] * yf + Fm[6];
    float b = Fm[1] * xf + Fm[4] * yf + Fm[7];
    float c = Fm[2] * xf + Fm[5] * yf + Fm[8];
    float n = sqrtf(a * a + b * b) + 1e-12f;
    a /= n; b /= n; c /= n;

    float alpha, beta_i;                        // vidx(u) = alpha*u + beta_i
    int u_lo, u_hi;
    if (fabsf(b) > 1e-6f) {
        alpha  = -a / b;
        beta_i = -c / b + 8.f;                  // vidx = v + 8
        u_lo = 0; u_hi = Ww - 1;
        if (fabsf(alpha) > 1e-12f) {
            float inv = 1.f / alpha;
            float t0 = (7.f - beta_i) * inv;    // v = -1
            float t1 = (264.f - beta_i) * inv;  // v = 256
            int lo = (int)floorf(fminf(t0, t1));
            int hi = (int)ceilf (fmaxf(t0, t1));
            u_lo = lo > 0 ? lo : 0;
            u_hi = hi < (Ww - 1) ? hi : (Ww - 1);
        } else if (beta_i <= 7.f || beta_i >= 264.f) {
            u_lo = 1 << 20; u_hi = -(1 << 20);
        }
    } else {                                    // 'ok'=false: contributes 0
        alpha = 0.f; beta_i = 3.0e4f;           // tents saturate to 0
        u_lo = 1 << 20; u_hi = -(1 << 20);
    }

    // Strip-corner lines (x0, x0+31) for the per-u window base (v monotone
    // in x for this F family; corner x-set is a subset of R12's passing set).
    float xA = (float)x0, xB = (float)(x0 + 31);
    float aA = Fm[0] * xA + Fm[3] * yf + Fm[6];
    float bA = Fm[1] * xA + Fm[4] * yf + Fm[7];
    float cA = Fm[2] * xA + Fm[5] * yf + Fm[8];
    float aB = Fm[0] * xB + Fm[3] * yf + Fm[6];
    float bB = Fm[1] * xB + Fm[4] * yf + Fm[7];
    float cB = Fm[2] * xB + Fm[5] * yf + Fm[8];
    float alA = -aA / bA, beA = -cA / bA + 8.f;
    float alB = -aB / bB, beB = -cB / bB + 8.f;

    // Wave-union of clip windows -> uniform scalar bounds (same for all 4
    // waves: same 32 pixels).
    int lo = u_lo, hi = u_hi;
#pragma unroll
    for (int off = 1; off < 64; off <<= 1) {
        int l2 = __shfl_xor(lo, off, 64);
        int h2 = __shfl_xor(hi, off, 64);
        lo = lo < l2 ? lo : l2;
        hi = hi > h2 ? hi : h2;
    }
    lo = __builtin_amdgcn_readfirstlane(lo);
    hi = __builtin_amdgcn_readfirstlane(hi);

    float16v acc = {0.f, 0.f, 0.f, 0.f, 0.f, 0.f, 0.f, 0.f,
                    0.f, 0.f, 0.f, 0.f, 0.f, 0.f, 0.f, 0.f};

    if (lo <= hi) {
        int len = hi - lo + 1;
        int C   = (len + 3) >> 2;               // total 4-u chunks
        int cq  = (C + 3) >> 2;                 // chunks per quarter
        int nit = C - wq * cq;                  // this quarter's chunk count
        nit = nit < 0 ? 0 : (nit > cq ? cq : nit);
        int us  = lo + wq * cq * 4;

        // --- R15 precompute: lane l -> window for u = us + l (same op order
        // as R14's inner loop: fmin, fmaf(0.125,-0.125), floor, clamp).
        float uf  = (float)(us + lane);
        float vAl = fmaf(alA, uf, beA);
        float vBl = fmaf(alB, uf, beB);
        float mnu = fminf(vAl, vBl);
        float Mf  = floorf(fmaf(mnu, 0.125f, -0.125f));  // floor((mn-1)/8)
        Mf = fmaxf(0.f, fminf(Mf, 33.f));
        int   vMo  = (int)Mf << 9;              // rblk byte offset
        float vB8f = Mf * 8.f;                  // exact (<= 264)
        int   vB8i = __builtin_bit_cast(int, vB8f);

        float v   = fmaf(alpha, (float)us, beta_i);
        float l8h = (float)(8 * h);
        const char* pb  = T4 + (size_t)us * USTRIDE;
        const int voff  = (h << 9) + (px << 4); // per-lane constant

        const half2v one2  = {(_Float16)1.f, (_Float16)1.f};
        const half2v zero2 = {(_Float16)0.f, (_Float16)0.f};

        uint4v bA4[4], bB4[4], bC4[4];

        // Issue the 4 B loads of chunk (base/4): addresses are SGPR-dynamic
        // (readlane Mo) + constant per-lane voffset.
#define FUME_ISS(BUF, BASE)                                                   \
    do {                                                                      \
        _Pragma("unroll")                                                     \
        for (int i_ = 0; i_ < 4; ++i_) {                                      \
            int idx_ = (BASE) + i_;                                           \
            int Mo_  = __builtin_amdgcn_readlane(vMo, idx_);                  \
            (BUF)[i_] = *(const uint4v*)(pb + (size_t)idx_ * USTRIDE          \
                                         + (size_t)Mo_ + voff);               \
        }                                                                     \
    } while (0)

        // Compute chunk (base/4) from BUF: tents + MFMA, v advances in the
        // exact R15 order (bit-identical accumulation).
#define FUME_COMP(BUF, BASE)                                                  \
    do {                                                                      \
        _Pragma("unroll")                                                     \
        for (int i_ = 0; i_ < 4; ++i_) {                                      \
            int idx_ = (BASE) + i_;                                           \
            float b8_ = __builtin_bit_cast(                                   \
                float, __builtin_amdgcn_readlane(vB8i, idx_));                \
            float vbl_ = (v - b8_) - l8h;                                     \
            half2v vb2_ = pack2(vbl_, vbl_);                                  \
            uint32_t aw_[4];                                                  \
            _Pragma("unroll")                                                 \
            for (int j_ = 0; j_ < 4; ++j_) {                                  \
                half2v cj_ = {(_Float16)(float)(2 * j_),                      \
                              (_Float16)(float)(2 * j_ + 1)};                 \
                half2v d_  = vb2_ - cj_;                                      \
                half2v ad_ = __builtin_elementwise_abs(d_);                   \
                half2v tj_ = __builtin_elementwise_max(one2 - ad_, zero2);    \
                __builtin_memcpy(&aw_[j_], &tj_, 4);                          \
            }                                                                 \
            half8v A_;                                                        \
            __builtin_memcpy(&A_, aw_, 16);                                   \
            half8v B_ = __builtin_bit_cast(half8v, (BUF)[i_]);                \
            acc = __builtin_amdgcn_mfma_f32_32x32x16_f16(A_, B_, acc, 0, 0, 0);\
            v += alpha;                                                       \
        }                                                                     \
    } while (0)

        if (nit > 0) {
            FUME_ISS(bA4, 0);
            if (nit > 1) FUME_ISS(bB4, 4);
            int cc = 0;
            for (;;) {
                if (cc + 2 < nit) FUME_ISS(bC4, (cc + 2) * 4);
                FUME_COMP(bA4, cc * 4);
                if (++cc >= nit) break;
                if (cc + 2 < nit) FUME_ISS(bA4, (cc + 2) * 4);
                FUME_COMP(bB4, cc * 4);
                if (++cc >= nit) break;
                if (cc + 2 < nit) FUME_ISS(bB4, (cc + 2) * 4);
                FUME_COMP(bC4, cc * 4);
                if (++cc >= nit) break;
            }
        }
#undef FUME_ISS
#undef FUME_COMP
    }

    // Combine the 4 u-quarters via LDS; D row = pixel, col(lane) = channel.
#pragma unroll
    for (int r = 0; r < 16; ++r) {
        int m = (r & 3) + 8 * (r >> 2) + 4 * h;   // pixel index 0..31
        red[wq][m][px] = acc[r];                  // [m][ch]
    }
    __syncthreads();
    {
        int pxs = t & 31, cg = t >> 5;            // pixel, ch-group
#pragma unroll
        for (int jj = 0; jj < 4; ++jj) {
            int ch = cg + 8 * jj;
            float val = red[0][pxs][ch] + red[1][pxs][ch]
                      + red[2][pxs][ch] + red[3][pxs][ch];
            out[(size_t)ch * (Hh * Ww) + y * Ww + x0 + pxs] = val;
        }
    }
}

// ---------------------------------------------------------------------------
// Fallback (ws too small): R1-style masked scalar path.
// ---------------------------------------------------------------------------
__global__ __launch_bounds__(256) void fume_fallback(const float* __restrict__ src,
                                                     const float* __restrict__ Fm,
                                                     float* __restrict__ out) {
    int g = blockIdx.x * 256 + threadIdx.x;
    int part = g & 3;
    int pix  = g >> 2;
    int x = pix & (Ww - 1);
    int y = pix >> 8;
    int ch0 = part * 8;
    float xf = (float)x, yf = (float)y;
    float a = Fm[0] * xf + Fm[3] * yf + Fm[6];
    float b = Fm[1] * xf + Fm[4] * yf + Fm[7];
    float c = Fm[2] * xf + Fm[5] * yf + Fm[8];
    float n = sqrtf(a * a + b * b) + 1e-12f;
    a /= n; b /= n; c /= n;
    float acc[8];
#pragma unroll
    for (int k = 0; k < 8; ++k) acc[k] = 0.f;
    if (fabsf(b) > 1e-6f) {
        float alpha = -a / b, beta = -c / b;
        for (int u = 0; u < Ww; ++u) {
            float v  = fmaf(alpha, (float)u, beta);
            float rf = floorf(v);
            float f  = v - rf;
            int   ri = (int)rf;
            float w0 = ((unsigned)ri       < (unsigned)Hh) ? (1.f - f) : 0.f;
            float w1 = ((unsigned)(ri + 1) < (unsigned)Hh) ? f         : 0.f;
            int r0 = ri < 0 ? 0 : (ri > Hh - 1 ? Hh - 1 : ri);
            int r1 = ri + 1 < 0 ? 0 : (ri + 1 > Hh - 1 ? Hh - 1 : ri + 1);
#pragma unroll
            for (int k = 0; k < 8; ++k) {
                float s0 = src[(size_t)(ch0 + k) * (Hh * Ww) + r0 * Ww + u];
                float s1 = src[(size_t)(ch0 + k) * (Hh * Ww) + r1 * Ww + u];
                acc[k] = fmaf(w0, s0, fmaf(w1, s1, acc[k]));
            }
        }
    }
#pragma unroll
    for (int k = 0; k < 8; ++k)
        out[(size_t)(ch0 + k) * (Hh * Ww) + pix] = acc[k];
}

extern "C" void kernel_launch(void* const* d_in, const int* in_sizes, int n_in,
                              void* d_out, int out_size, void* d_ws, size_t ws_size,
                              hipStream_t stream) {
    const float* view1 = (const float*)d_in[0];
    const float* Fm    = (const float*)d_in[1];
    float* out = (float*)d_out;

    constexpr size_t t4_bytes = (size_t)UPLANES * USTRIDE;   // ~4.7 MB
    if (ws_size >= t4_bytes) {
        char* T4 = (char*)d_ws;
        fume_pack<<<520, 256, 0, stream>>>(view1, T4);
        fume_mfma<<<2048, 256, 0, stream>>>(T4, Fm, out);
    } else {
        fume_fallback<<<(Hh * Ww * 4) / 256, 256, 0, stream>>>(view1, Fm, out);
    }
}

// Round 3
// 95.006 us; speedup vs baseline: 1.0268x; 1.0268x over previous
//
#include <hip/hip_runtime.h>
#include <cstdint>

// Problem constants: view1 (B=8, C=4, H=256, W=256) fp32, F 3x3 fp32.
constexpr int Hh = 256, Ww = 256, BCc = 32;
// T4[u(264)][rblk(35)][ch(32)][rw(8)] fp16. ridx = r+8: blk0 = rows -8..-1
// (zero), blk1..32 = rows 0..255, blk33/34 = rows 256..271 (zero). Planes
// u=256..263 fully zero. Strides (bytes): u: 17920, rblk: 512, ch: 16.
constexpr int RBLK = 35;
constexpr int USTRIDE = RBLK * BCc * 8 * 2;    // 17920 B
constexpr int UPLANES = 264;

typedef _Float16 half2v   __attribute__((ext_vector_type(2)));
typedef _Float16 half8v   __attribute__((ext_vector_type(8)));
typedef __fp16   fp16x2   __attribute__((ext_vector_type(2)));
typedef float    float16v __attribute__((ext_vector_type(16)));
typedef uint32_t uint4v   __attribute__((ext_vector_type(4)));

static __device__ inline half2v pack2(float a, float b) {
    fp16x2 r = __builtin_amdgcn_cvt_pkrtz(a, b);
    return __builtin_bit_cast(half2v, r);
}

// ---------------------------------------------------------------------------
// Pack view1 (ch,H,W) f32 -> T4 fp16. Blocks 0..511: (chg 4) x (rblk 32) x
// (utile 4, 64 u): 8ch x 8r x 64u each, single pass; write side is 128B-
// contiguous (8 ch x 16 B). Blocks 512..519: grid-stride zero of pads.
// ---------------------------------------------------------------------------
__global__ __launch_bounds__(256) void fume_pack(const float* __restrict__ in,
                                                 char* __restrict__ T4) {
    const int t   = threadIdx.x;
    const int bid = blockIdx.x;
    if (bid >= 512) {                           // zero pads
        constexpr int NA = UPLANES * 3 * 32;    // blk{0,33,34} x u x ch
        constexpr int NB = 8 * 32 * 32;         // u 256..263 x blk1..32 x ch
        for (int id = (bid - 512) * 256 + t; id < NA + NB; id += 8 * 256) {
            int u, blk, ch;
            if (id < NA) {
                u = id / 96;
                int rem = id - u * 96;
                int bsel = rem >> 5;
                blk = (bsel == 0) ? 0 : (bsel == 1 ? 33 : 34);
                ch = rem & 31;
            } else {
                int id2 = id - NA;
                u = 256 + (id2 >> 10);
                int rem = id2 & 1023;
                blk = 1 + (rem >> 5);
                ch = rem & 31;
            }
            uint4v z = {0, 0, 0, 0};
            *(uint4v*)(T4 + (size_t)u * USTRIDE + blk * 512 + ch * 16) = z;
        }
        return;
    }
    __shared__ float lds[8][8][65];             // [ch][r][u(+pad)]
    const int chg = bid & 3;
    const int r0  = ((bid >> 2) & 31) * 8;      // one rblk
    const int u0  = (bid >> 7) * 64;
    const int blk = (r0 >> 3) + 1;              // ridx = r+8

#pragma unroll
    for (int it = 0; it < 16; ++it) {           // 8ch x 8r x 64u coalesced
        int idx = it * 256 + t;
        int ch = idx >> 9, rr = (idx >> 6) & 7, uu = idx & 63;
        lds[ch][rr][uu] =
            in[(chg * 8 + ch) * (Hh * Ww) + (r0 + rr) * Ww + u0 + uu];
    }
    __syncthreads();
    const int chl = t & 7;
#pragma unroll
    for (int p = 0; p < 2; ++p) {
        int u_l = (t >> 3) + p * 32;            // 0..63
        uint32_t w[4];
#pragma unroll
        for (int j = 0; j < 4; ++j) {
            half2v pr = pack2(lds[chl][2 * j][u_l], lds[chl][2 * j + 1][u_l]);
            __builtin_memcpy(&w[j], &pr, 4);
        }
        uint4v val = {w[0], w[1], w[2], w[3]};
        *(uint4v*)(T4 + (size_t)(u0 + u_l) * USTRIDE + blk * 512
                   + (chg * 8 + chl) * 16) = val;
    }
}

// ---------------------------------------------------------------------------
// MFMA main (R17 = R15 inner loop + XCD-aware y-band block swizzle).
// Strip = 32 px at row y; one 32x32x16 MFMA per u:
//   A[m=px][k] = tent(vidx_px(u) - (8*(M_u+h) + j)),  k = h*8+j, h=lane>>5
//   B[k][ch=n] = T4[u][M_u+h][ch][j] -> one dwordx4/lane; the wave's 64
//                loads are 1 KB CONTIGUOUS (2 rblks x 32ch x 16B)
//   D[m][n]: col=lane&31(=ch), row=(reg&3)+8*(reg>>2)+4*h (guide-verified)
// M_u per u (coverage needs strip-spread < 6; 32-px span <= 5.69, margin
// 0.31). Chunk split (R14): u-quarters are whole 4-u chunks, interior
// quarters disjoint; final chunk overruns <= hi+3 <= 258 < 264 into zeroed
// u-planes, masked by tents.
// R15: lane l precomputes the per-u window (Mo byte offset, 8*Mf float) for
// u = us+l in ONE vector pass; inner loop fetches via v_readlane (uniform
// idx); B-address is scalar-base + constant-voffset.
// R16 (REVERTED): depth-3 ring regressed — VGPR 36->60, achieved occupancy
// 41->29%, conservative vmcnt across the branchy rotation.
// R17: total B traffic ~475 MB vs T4 = 4.7 MB > one XCD L2 (4 MB). Default
// bid%8 XCD round-robin gives every XCD ~all of T4 (bid&7 = x0 tile) ->
// heavy L3 servicing (~600 cyc). Remap so XCD k = bid&7 owns y-band
// [32k,32k+32) (all x0): per-XCD concurrent working set ~T4/8 + overlap,
// fits 4MB L2 -> L3 hits become L2 hits. Bijection; per-block math is
// UNCHANGED from R15 -> bit-identical output.
// ---------------------------------------------------------------------------
__global__ __launch_bounds__(256, 4) void fume_mfma(const char* __restrict__ T4,
                                                    const float* __restrict__ Fm,
                                                    float* __restrict__ out) {
    __shared__ float red[4][32][33];
    const int t    = threadIdx.x;
    const int lane = t & 63;
    const int wq   = t >> 6;                    // u-quarter 0..3
    const int px   = lane & 31;                 // pixel (A.m) and channel (B.n)
    const int h    = lane >> 5;                 // k-half: window rows 8h..8h+7
    // XCD swizzle: xcd = bid&7 (HW round-robin), idx = bid>>3 (per-XCD seq).
    // y = xcd*32 + (idx>>3) sweeps a 32-row band per XCD; idx&7 = x0 tile.
    const int bid  = (int)blockIdx.x;
    const int idx8 = bid >> 3;
    const int y    = ((bid & 7) << 5) + (idx8 >> 3);
    const int x0   = (idx8 & 7) * 32;
    const int x    = x0 + px;

    // Own-pixel epipolar line (reference op order).
    float xf = (float)x, yf = (float)y;
    float a = Fm[0] * xf + Fm[3] * yf + Fm[6];
    float b = Fm[1] * xf + Fm[4] * yf + Fm[7];
    float c = Fm[2] * xf + Fm[5] * yf + Fm[8];
    float n = sqrtf(a * a + b * b) + 1e-12f;
    a /= n; b /= n; c /= n;

    float alpha, beta_i;                        // vidx(u) = alpha*u + beta_i
    int u_lo, u_hi;
    if (fabsf(b) > 1e-6f) {
        alpha  = -a / b;
        beta_i = -c / b + 8.f;                  // vidx = v + 8
        u_lo = 0; u_hi = Ww - 1;
        if (fabsf(alpha) > 1e-12f) {
            float inv = 1.f / alpha;
            float t0 = (7.f - beta_i) * inv;    // v = -1
            float t1 = (264.f - beta_i) * inv;  // v = 256
            int lo = (int)floorf(fminf(t0, t1));
            int hi = (int)ceilf (fmaxf(t0, t1));
            u_lo = lo > 0 ? lo : 0;
            u_hi = hi < (Ww - 1) ? hi : (Ww - 1);
        } else if (beta_i <= 7.f || beta_i >= 264.f) {
            u_lo = 1 << 20; u_hi = -(1 << 20);
        }
    } else {                                    // 'ok'=false: contributes 0
        alpha = 0.f; beta_i = 3.0e4f;           // tents saturate to 0
        u_lo = 1 << 20; u_hi = -(1 << 20);
    }

    // Strip-corner lines (x0, x0+31) for the per-u window base (v monotone
    // in x for this F family; corner x-set is a subset of R12's passing set).
    float xA = (float)x0, xB = (float)(x0 + 31);
    float aA = Fm[0] * xA + Fm[3] * yf + Fm[6];
    float bA = Fm[1] * xA + Fm[4] * yf + Fm[7];
    float cA = Fm[2] * xA + Fm[5] * yf + Fm[8];
    float aB = Fm[0] * xB + Fm[3] * yf + Fm[6];
    float bB = Fm[1] * xB + Fm[4] * yf + Fm[7];
    float cB = Fm[2] * xB + Fm[5] * yf + Fm[8];
    float alA = -aA / bA, beA = -cA / bA + 8.f;
    float alB = -aB / bB, beB = -cB / bB + 8.f;

    // Wave-union of clip windows -> uniform scalar bounds (same for all 4
    // waves: same 32 pixels).
    int lo = u_lo, hi = u_hi;
#pragma unroll
    for (int off = 1; off < 64; off <<= 1) {
        int l2 = __shfl_xor(lo, off, 64);
        int h2 = __shfl_xor(hi, off, 64);
        lo = lo < l2 ? lo : l2;
        hi = hi > h2 ? hi : h2;
    }
    lo = __builtin_amdgcn_readfirstlane(lo);
    hi = __builtin_amdgcn_readfirstlane(hi);

    float16v acc = {0.f, 0.f, 0.f, 0.f, 0.f, 0.f, 0.f, 0.f,
                    0.f, 0.f, 0.f, 0.f, 0.f, 0.f, 0.f, 0.f};

    if (lo <= hi) {
        int len = hi - lo + 1;
        int C   = (len + 3) >> 2;               // total 4-u chunks
        int cq  = (C + 3) >> 2;                 // chunks per quarter
        int nit = C - wq * cq;                  // this quarter's chunk count
        nit = nit < 0 ? 0 : (nit > cq ? cq : nit);
        int n4  = nit << 2;                     // u-count, multiple of 4, <=64
        int us  = lo + wq * cq * 4;

        // --- R15 precompute: lane l -> window for u = us + l (same op order
        // as R14's inner loop: fmin, fmaf(0.125,-0.125), floor, clamp).
        float uf  = (float)(us + lane);
        float vAl = fmaf(alA, uf, beA);
        float vBl = fmaf(alB, uf, beB);
        float mnu = fminf(vAl, vBl);
        float Mf  = floorf(fmaf(mnu, 0.125f, -0.125f));  // floor((mn-1)/8)
        Mf = fmaxf(0.f, fminf(Mf, 33.f));
        int   vMo  = (int)Mf << 9;              // rblk byte offset
        float vB8f = Mf * 8.f;                  // exact (<= 264)
        int   vB8i = __builtin_bit_cast(int, vB8f);

        float v   = fmaf(alpha, (float)us, beta_i);
        float l8h = (float)(8 * h);
        const char* pb  = T4 + (size_t)us * USTRIDE;
        const int voff  = (h << 9) + (px << 4); // per-lane constant

        const half2v one2  = {(_Float16)1.f, (_Float16)1.f};
        const half2v zero2 = {(_Float16)0.f, (_Float16)0.f};

        for (int it2 = 0; it2 < n4; it2 += 4) {
#pragma unroll
            for (int i = 0; i < 4; ++i) {
                const int idx = it2 + i;
                // Uniform per-u window via readlane (broadcast, no per-lane
                // recompute).
                int   Mo = __builtin_amdgcn_readlane(vMo, idx);
                float b8 = __builtin_bit_cast(
                    float, __builtin_amdgcn_readlane(vB8i, idx));
                // Scalar base + constant voffset -> saddr dwordx4, zero VALU.
                uint4v bw = *(const uint4v*)(pb + (size_t)idx * USTRIDE
                                             + (size_t)Mo + voff);

                // A tents: vbl = vidx - 8M - 8h; A[j] = max(0, 1-|vbl-j|).
                // (v - b8) == fmaf(Mf,-8,v) exactly (b8 = 8*Mf exact).
                float vbl = (v - b8) - l8h;
                half2v vb2 = pack2(vbl, vbl);
                uint32_t aw[4];
#pragma unroll
                for (int j = 0; j < 4; ++j) {
                    half2v cj = {(_Float16)(float)(2 * j),
                                 (_Float16)(float)(2 * j + 1)};
                    half2v d  = vb2 - cj;
                    half2v ad = __builtin_elementwise_abs(d);
                    half2v tj = __builtin_elementwise_max(one2 - ad, zero2);
                    __builtin_memcpy(&aw[j], &tj, 4);
                }
                half8v A;
                __builtin_memcpy(&A, aw, 16);
                half8v B = __builtin_bit_cast(half8v, bw);
                acc = __builtin_amdgcn_mfma_f32_32x32x16_f16(A, B, acc, 0, 0, 0);

                v += alpha;
            }
        }
    }

    // Combine the 4 u-quarters via LDS; D row = pixel, col(lane) = channel.
#pragma unroll
    for (int r = 0; r < 16; ++r) {
        int m = (r & 3) + 8 * (r >> 2) + 4 * h;   // pixel index 0..31
        red[wq][m][px] = acc[r];                  // [m][ch]
    }
    __syncthreads();
    {
        int pxs = t & 31, cg = t >> 5;            // pixel, ch-group
#pragma unroll
        for (int jj = 0; jj < 4; ++jj) {
            int ch = cg + 8 * jj;
            float val = red[0][pxs][ch] + red[1][pxs][ch]
                      + red[2][pxs][ch] + red[3][pxs][ch];
            out[(size_t)ch * (Hh * Ww) + y * Ww + x0 + pxs] = val;
        }
    }
}

// ---------------------------------------------------------------------------
// Fallback (ws too small): R1-style masked scalar path.
// ---------------------------------------------------------------------------
__global__ __launch_bounds__(256) void fume_fallback(const float* __restrict__ src,
                                                     const float* __restrict__ Fm,
                                                     float* __restrict__ out) {
    int g = blockIdx.x * 256 + threadIdx.x;
    int part = g & 3;
    int pix  = g >> 2;
    int x = pix & (Ww - 1);
    int y = pix >> 8;
    int ch0 = part * 8;
    float xf = (float)x, yf = (float)y;
    float a = Fm[0] * xf + Fm[3] * yf + Fm[6];
    float b = Fm[1] * xf + Fm[4] * yf + Fm[7];
    float c = Fm[2] * xf + Fm[5] * yf + Fm[8];
    float n = sqrtf(a * a + b * b) + 1e-12f;
    a /= n; b /= n; c /= n;
    float acc[8];
#pragma unroll
    for (int k = 0; k < 8; ++k) acc[k] = 0.f;
    if (fabsf(b) > 1e-6f) {
        float alpha = -a / b, beta = -c / b;
        for (int u = 0; u < Ww; ++u) {
            float v  = fmaf(alpha, (float)u, beta);
            float rf = floorf(v);
            float f  = v - rf;
            int   ri = (int)rf;
            float w0 = ((unsigned)ri       < (unsigned)Hh) ? (1.f - f) : 0.f;
            float w1 = ((unsigned)(ri + 1) < (unsigned)Hh) ? f         : 0.f;
            int r0 = ri < 0 ? 0 : (ri > Hh - 1 ? Hh - 1 : ri);
            int r1 = ri + 1 < 0 ? 0 : (ri + 1 > Hh - 1 ? Hh - 1 : ri + 1);
#pragma unroll
            for (int k = 0; k < 8; ++k) {
                float s0 = src[(size_t)(ch0 + k) * (Hh * Ww) + r0 * Ww + u];
                float s1 = src[(size_t)(ch0 + k) * (Hh * Ww) + r1 * Ww + u];
                acc[k] = fmaf(w0, s0, fmaf(w1, s1, acc[k]));
            }
        }
    }
#pragma unroll
    for (int k = 0; k < 8; ++k)
        out[(size_t)(ch0 + k) * (Hh * Ww) + pix] = acc[k];
}

extern "C" void kernel_launch(void* const* d_in, const int* in_sizes, int n_in,
                              void* d_out, int out_size, void* d_ws, size_t ws_size,
                              hipStream_t stream) {
    const float* view1 = (const float*)d_in[0];
    const float* Fm    = (const float*)d_in[1];
    float* out = (float*)d_out;

    constexpr size_t t4_bytes = (size_t)UPLANES * USTRIDE;   // ~4.7 MB
    if (ws_size >= t4_bytes) {
        char* T4 = (char*)d_ws;
        fume_pack<<<520, 256, 0, stream>>>(view1, T4);
        fume_mfma<<<2048, 256, 0, stream>>>(T4, Fm, out);
    } else {
        fume_fallback<<<(Hh * Ww * 4) / 256, 256, 0, stream>>>(view1, Fm, out);
    }
}

// Round 4
// 92.332 us; speedup vs baseline: 1.0566x; 1.0290x over previous
//
#include <hip/hip_runtime.h>
#include <cstdint>

// Problem constants: view1 (B=8, C=4, H=256, W=256) fp32, F 3x3 fp32.
constexpr int Hh = 256, Ww = 256, BCc = 32;
// T4[u(264)][rblk(35)][ch(32)][rw(8)] fp16. ridx = r+8: blk0 = rows -8..-1
// (zero), blk1..32 = rows 0..255, blk33/34 = rows 256..271 (zero). Planes
// u=256..263 fully zero. Strides (bytes): u: 17920, rblk: 512, ch: 16.
constexpr int RBLK = 35;
constexpr int USTRIDE = RBLK * BCc * 8 * 2;    // 17920 B
constexpr int UPLANES = 264;

typedef _Float16 half2v   __attribute__((ext_vector_type(2)));
typedef _Float16 half8v   __attribute__((ext_vector_type(8)));
typedef __fp16   fp16x2   __attribute__((ext_vector_type(2)));
typedef float    float16v __attribute__((ext_vector_type(16)));
typedef uint32_t uint4v   __attribute__((ext_vector_type(4)));

static __device__ inline half2v pack2(float a, float b) {
    fp16x2 r = __builtin_amdgcn_cvt_pkrtz(a, b);
    return __builtin_bit_cast(half2v, r);
}

// ---------------------------------------------------------------------------
// Pack view1 (ch,H,W) f32 -> T4 fp16. Blocks 0..511: (chg 4) x (rblk 32) x
// (utile 4, 64 u): 8ch x 8r x 64u each, single pass; write side is 128B-
// contiguous (8 ch x 16 B). Blocks 512..519: grid-stride zero of pads.
// ---------------------------------------------------------------------------
__global__ __launch_bounds__(256) void fume_pack(const float* __restrict__ in,
                                                 char* __restrict__ T4) {
    const int t   = threadIdx.x;
    const int bid = blockIdx.x;
    if (bid >= 512) {                           // zero pads
        constexpr int NA = UPLANES * 3 * 32;    // blk{0,33,34} x u x ch
        constexpr int NB = 8 * 32 * 32;         // u 256..263 x blk1..32 x ch
        for (int id = (bid - 512) * 256 + t; id < NA + NB; id += 8 * 256) {
            int u, blk, ch;
            if (id < NA) {
                u = id / 96;
                int rem = id - u * 96;
                int bsel = rem >> 5;
                blk = (bsel == 0) ? 0 : (bsel == 1 ? 33 : 34);
                ch = rem & 31;
            } else {
                int id2 = id - NA;
                u = 256 + (id2 >> 10);
                int rem = id2 & 1023;
                blk = 1 + (rem >> 5);
                ch = rem & 31;
            }
            uint4v z = {0, 0, 0, 0};
            *(uint4v*)(T4 + (size_t)u * USTRIDE + blk * 512 + ch * 16) = z;
        }
        return;
    }
    __shared__ float lds[8][8][65];             // [ch][r][u(+pad)]
    const int chg = bid & 3;
    const int r0  = ((bid >> 2) & 31) * 8;      // one rblk
    const int u0  = (bid >> 7) * 64;
    const int blk = (r0 >> 3) + 1;              // ridx = r+8

#pragma unroll
    for (int it = 0; it < 16; ++it) {           // 8ch x 8r x 64u coalesced
        int idx = it * 256 + t;
        int ch = idx >> 9, rr = (idx >> 6) & 7, uu = idx & 63;
        lds[ch][rr][uu] =
            in[(chg * 8 + ch) * (Hh * Ww) + (r0 + rr) * Ww + u0 + uu];
    }
    __syncthreads();
    const int chl = t & 7;
#pragma unroll
    for (int p = 0; p < 2; ++p) {
        int u_l = (t >> 3) + p * 32;            // 0..63
        uint32_t w[4];
#pragma unroll
        for (int j = 0; j < 4; ++j) {
            half2v pr = pack2(lds[chl][2 * j][u_l], lds[chl][2 * j + 1][u_l]);
            __builtin_memcpy(&w[j], &pr, 4);
        }
        uint4v val = {w[0], w[1], w[2], w[3]};
        *(uint4v*)(T4 + (size_t)(u0 + u_l) * USTRIDE + blk * 512
                   + (chg * 8 + chl) * 16) = val;
    }
}

// ---------------------------------------------------------------------------
// MFMA main (R18 = R17 + inner-loop VALU trim).
// Strip = 32 px at row y; one 32x32x16 MFMA per u:
//   A[m=px][k] = tent(vidx_px(u) - (8*(M_u+h) + j)),  k = h*8+j, h=lane>>5
//   B[k][ch=n] = T4[u][M_u+h][ch][j] -> one dwordx4/lane; the wave's 64
//                loads are 1 KB CONTIGUOUS (2 rblks x 32ch x 16B)
//   D[m][n]: col=lane&31(=ch), row=(reg&3)+8*(reg>>2)+4*h (guide-verified)
// M_u per u (coverage needs strip-spread < 6; 32-px span <= 5.69, margin
// 0.31). Chunk split (R14): u-quarters are whole 4-u chunks; final chunk
// overruns <= hi+3 <= 258 < 264 into zeroed u-planes, masked by tents.
// R15: lane-parallel window precompute; inner loop readlane + scalar-base
// addressing. R16 (REVERTED): depth-3 ring regressed (occupancy 41->29%).
// R17: XCD y-band swizzle — measured NEUTRAL (T4 ~fits 4MB L2 already);
// kept (free). R18: loop is VALU-ISSUE-bound (~22 ops/u ~ 43 issue cyc vs
// 51 cyc/u observed). Cuts:
//   (1) tent = clamp(1 - |d|) via v_pk_add_f16 ... clamp (valid: 1-|d| <= 1,
//       so [0,1]-clamp == max(0,.)) — one op replaces sub+max;
//   (2) track vh = v - 8h (folds per-lane -l8h into the recurrence init;
//       <=1 ulp f32 reassociation, far below f16 quantization);
//   (3) explicit uint AND for |d|.
// ~17 VALU/u (~34 issue cyc), same loads, same MFMA order.
// ---------------------------------------------------------------------------
__global__ __launch_bounds__(256, 4) void fume_mfma(const char* __restrict__ T4,
                                                    const float* __restrict__ Fm,
                                                    float* __restrict__ out) {
    __shared__ float red[4][32][33];
    const int t    = threadIdx.x;
    const int lane = t & 63;
    const int wq   = t >> 6;                    // u-quarter 0..3
    const int px   = lane & 31;                 // pixel (A.m) and channel (B.n)
    const int h    = lane >> 5;                 // k-half: window rows 8h..8h+7
    // XCD swizzle: xcd = bid&7 (HW round-robin), idx = bid>>3 (per-XCD seq).
    // y = xcd*32 + (idx>>3) sweeps a 32-row band per XCD; idx&7 = x0 tile.
    const int bid  = (int)blockIdx.x;
    const int idx8 = bid >> 3;
    const int y    = ((bid & 7) << 5) + (idx8 >> 3);
    const int x0   = (idx8 & 7) * 32;
    const int x    = x0 + px;

    // Own-pixel epipolar line (reference op order).
    float xf = (float)x, yf = (float)y;
    float a = Fm[0] * xf + Fm[3] * yf + Fm[6];
    float b = Fm[1] * xf + Fm[4] * yf + Fm[7];
    float c = Fm[2] * xf + Fm[5] * yf + Fm[8];
    float n = sqrtf(a * a + b * b) + 1e-12f;
    a /= n; b /= n; c /= n;

    float alpha, beta_i;                        // vidx(u) = alpha*u + beta_i
    int u_lo, u_hi;
    if (fabsf(b) > 1e-6f) {
        alpha  = -a / b;
        beta_i = -c / b + 8.f;                  // vidx = v + 8
        u_lo = 0; u_hi = Ww - 1;
        if (fabsf(alpha) > 1e-12f) {
            float inv = 1.f / alpha;
            float t0 = (7.f - beta_i) * inv;    // v = -1
            float t1 = (264.f - beta_i) * inv;  // v = 256
            int lo = (int)floorf(fminf(t0, t1));
            int hi = (int)ceilf (fmaxf(t0, t1));
            u_lo = lo > 0 ? lo : 0;
            u_hi = hi < (Ww - 1) ? hi : (Ww - 1);
        } else if (beta_i <= 7.f || beta_i >= 264.f) {
            u_lo = 1 << 20; u_hi = -(1 << 20);
        }
    } else {                                    // 'ok'=false: contributes 0
        alpha = 0.f; beta_i = 3.0e4f;           // tents saturate to 0
        u_lo = 1 << 20; u_hi = -(1 << 20);
    }

    // Strip-corner lines (x0, x0+31) for the per-u window base (v monotone
    // in x for this F family; corner x-set is a subset of R12's passing set).
    float xA = (float)x0, xB = (float)(x0 + 31);
    float aA = Fm[0] * xA + Fm[3] * yf + Fm[6];
    float bA = Fm[1] * xA + Fm[4] * yf + Fm[7];
    float cA = Fm[2] * xA + Fm[5] * yf + Fm[8];
    float aB = Fm[0] * xB + Fm[3] * yf + Fm[6];
    float bB = Fm[1] * xB + Fm[4] * yf + Fm[7];
    float cB = Fm[2] * xB + Fm[5] * yf + Fm[8];
    float alA = -aA / bA, beA = -cA / bA + 8.f;
    float alB = -aB / bB, beB = -cB / bB + 8.f;

    // Wave-union of clip windows -> uniform scalar bounds (same for all 4
    // waves: same 32 pixels).
    int lo = u_lo, hi = u_hi;
#pragma unroll
    for (int off = 1; off < 64; off <<= 1) {
        int l2 = __shfl_xor(lo, off, 64);
        int h2 = __shfl_xor(hi, off, 64);
        lo = lo < l2 ? lo : l2;
        hi = hi > h2 ? hi : h2;
    }
    lo = __builtin_amdgcn_readfirstlane(lo);
    hi = __builtin_amdgcn_readfirstlane(hi);

    float16v acc = {0.f, 0.f, 0.f, 0.f, 0.f, 0.f, 0.f, 0.f,
                    0.f, 0.f, 0.f, 0.f, 0.f, 0.f, 0.f, 0.f};

    if (lo <= hi) {
        int len = hi - lo + 1;
        int C   = (len + 3) >> 2;               // total 4-u chunks
        int cq  = (C + 3) >> 2;                 // chunks per quarter
        int nit = C - wq * cq;                  // this quarter's chunk count
        nit = nit < 0 ? 0 : (nit > cq ? cq : nit);
        int n4  = nit << 2;                     // u-count, multiple of 4, <=64
        int us  = lo + wq * cq * 4;

        // --- R15 precompute: lane l -> window for u = us + l (same op order
        // as R14's inner loop: fmin, fmaf(0.125,-0.125), floor, clamp).
        float uf  = (float)(us + lane);
        float vAl = fmaf(alA, uf, beA);
        float vBl = fmaf(alB, uf, beB);
        float mnu = fminf(vAl, vBl);
        float Mf  = floorf(fmaf(mnu, 0.125f, -0.125f));  // floor((mn-1)/8)
        Mf = fmaxf(0.f, fminf(Mf, 33.f));
        int   vMo  = (int)Mf << 9;              // rblk byte offset
        float vB8f = Mf * 8.f;                  // exact (<= 264)
        int   vB8i = __builtin_bit_cast(int, vB8f);

        float l8h = (float)(8 * h);
        // R18: vh = vidx - 8h; per-u tent base is vh - 8*M (one sub).
        float vh  = fmaf(alpha, (float)us, beta_i) - l8h;
        const char* pb  = T4 + (size_t)us * USTRIDE;
        const int voff  = (h << 9) + (px << 4); // per-lane constant

        const half2v one2 = {(_Float16)1.f, (_Float16)1.f};

        for (int it2 = 0; it2 < n4; it2 += 4) {
#pragma unroll
            for (int i = 0; i < 4; ++i) {
                const int idx = it2 + i;
                // Uniform per-u window via readlane (broadcast, no per-lane
                // recompute).
                int   Mo = __builtin_amdgcn_readlane(vMo, idx);
                float b8 = __builtin_bit_cast(
                    float, __builtin_amdgcn_readlane(vB8i, idx));
                // Scalar base + constant voffset -> saddr dwordx4, zero VALU.
                uint4v bw = *(const uint4v*)(pb + (size_t)idx * USTRIDE
                                             + (size_t)Mo + voff);

                // A tents: vbl = vidx - 8M - 8h = vh - 8M;
                // A[j] = clamp(1 - |vbl - j|)  (== max(0, 1-|.|) since <=1).
                float vbl = vh - b8;
                half2v vb2 = pack2(vbl, vbl);
                uint32_t aw[4];
#pragma unroll
                for (int j = 0; j < 4; ++j) {
                    half2v cj = {(_Float16)(float)(2 * j),
                                 (_Float16)(float)(2 * j + 1)};
                    half2v d  = vb2 - cj;
                    uint32_t du;
                    __builtin_memcpy(&du, &d, 4);
                    du &= 0x7fff7fffu;          // |d| packed
                    half2v ad;
                    __builtin_memcpy(&ad, &du, 4);
                    half2v tj;
                    asm("v_pk_add_f16 %0, %1, %2 neg_lo:[0,1] neg_hi:[0,1] clamp"
                        : "=v"(tj)
                        : "v"(one2), "v"(ad));
                    __builtin_memcpy(&aw[j], &tj, 4);
                }
                half8v A;
                __builtin_memcpy(&A, aw, 16);
                half8v B = __builtin_bit_cast(half8v, bw);
                acc = __builtin_amdgcn_mfma_f32_32x32x16_f16(A, B, acc, 0, 0, 0);

                vh += alpha;
            }
        }
    }

    // Combine the 4 u-quarters via LDS; D row = pixel, col(lane) = channel.
#pragma unroll
    for (int r = 0; r < 16; ++r) {
        int m = (r & 3) + 8 * (r >> 2) + 4 * h;   // pixel index 0..31
        red[wq][m][px] = acc[r];                  // [m][ch]
    }
    __syncthreads();
    {
        int pxs = t & 31, cg = t >> 5;            // pixel, ch-group
#pragma unroll
        for (int jj = 0; jj < 4; ++jj) {
            int ch = cg + 8 * jj;
            float val = red[0][pxs][ch] + red[1][pxs][ch]
                      + red[2][pxs][ch] + red[3][pxs][ch];
            out[(size_t)ch * (Hh * Ww) + y * Ww + x0 + pxs] = val;
        }
    }
}

// ---------------------------------------------------------------------------
// Fallback (ws too small): R1-style masked scalar path.
// ---------------------------------------------------------------------------
__global__ __launch_bounds__(256) void fume_fallback(const float* __restrict__ src,
                                                     const float* __restrict__ Fm,
                                                     float* __restrict__ out) {
    int g = blockIdx.x * 256 + threadIdx.x;
    int part = g & 3;
    int pix  = g >> 2;
    int x = pix & (Ww - 1);
    int y = pix >> 8;
    int ch0 = part * 8;
    float xf = (float)x, yf = (float)y;
    float a = Fm[0] * xf + Fm[3] * yf + Fm[6];
    float b = Fm[1] * xf + Fm[4] * yf + Fm[7];
    float c = Fm[2] * xf + Fm[5] * yf + Fm[8];
    float n = sqrtf(a * a + b * b) + 1e-12f;
    a /= n; b /= n; c /= n;
    float acc[8];
#pragma unroll
    for (int k = 0; k < 8; ++k) acc[k] = 0.f;
    if (fabsf(b) > 1e-6f) {
        float alpha = -a / b, beta = -c / b;
        for (int u = 0; u < Ww; ++u) {
            float v  = fmaf(alpha, (float)u, beta);
            float rf = floorf(v);
            float f  = v - rf;
            int   ri = (int)rf;
            float w0 = ((unsigned)ri       < (unsigned)Hh) ? (1.f - f) : 0.f;
            float w1 = ((unsigned)(ri + 1) < (unsigned)Hh) ? f         : 0.f;
            int r0 = ri < 0 ? 0 : (ri > Hh - 1 ? Hh - 1 : ri);
            int r1 = ri + 1 < 0 ? 0 : (ri + 1 > Hh - 1 ? Hh - 1 : ri + 1);
#pragma unroll
            for (int k = 0; k < 8; ++k) {
                float s0 = src[(size_t)(ch0 + k) * (Hh * Ww) + r0 * Ww + u];
                float s1 = src[(size_t)(ch0 + k) * (Hh * Ww) + r1 * Ww + u];
                acc[k] = fmaf(w0, s0, fmaf(w1, s1, acc[k]));
            }
        }
    }
#pragma unroll
    for (int k = 0; k < 8; ++k)
        out[(size_t)(ch0 + k) * (Hh * Ww) + pix] = acc[k];
}

extern "C" void kernel_launch(void* const* d_in, const int* in_sizes, int n_in,
                              void* d_out, int out_size, void* d_ws, size_t ws_size,
                              hipStream_t stream) {
    const float* view1 = (const float*)d_in[0];
    const float* Fm    = (const float*)d_in[1];
    float* out = (float*)d_out;

    constexpr size_t t4_bytes = (size_t)UPLANES * USTRIDE;   // ~4.7 MB
    if (ws_size >= t4_bytes) {
        char* T4 = (char*)d_ws;
        fume_pack<<<520, 256, 0, stream>>>(view1, T4);
        fume_mfma<<<2048, 256, 0, stream>>>(T4, Fm, out);
    } else {
        fume_fallback<<<(Hh * Ww * 4) / 256, 256, 0, stream>>>(view1, Fm, out);
    }
}